// Round 7
// baseline (241.336 us; speedup 1.0000x reference)
//
#include <hip/hip_runtime.h>
#include <hip/hip_bf16.h>

#define D 128
#define KTERMS 16

typedef __attribute__((ext_vector_type(8))) short bf16x8;
typedef __attribute__((ext_vector_type(4))) float f32x4;

__device__ inline short rne_bf16(float f) {
    union { float f; unsigned u; } v; v.f = f;
    unsigned r = (v.u + 0x7fffu + ((v.u >> 16) & 1u)) >> 16;
    return (short)r;
}
__device__ inline float bf16_to_f(unsigned s) {
    union { unsigned u; float f; } v; v.u = s << 16;
    return v.f;
}

// ---------- prep: blocks [0,1024) convert x->bf16; blocks [1024,1280) build concat weights ----------
__global__ __launch_bounds__(256) void prep_kernel(const float* __restrict__ x,
                                                   short* __restrict__ xb,
                                                   const float* __restrict__ W1l,
                                                   const float* __restrict__ W1r,
                                                   const float* __restrict__ W2l,
                                                   const float* __restrict__ W2r,
                                                   short* __restrict__ Bc1,
                                                   short* __restrict__ Bc2) {
    int b = blockIdx.x;
    if (b < 1024) {
        int base = (b * 256 + threadIdx.x) * 8;
        const float4 a = *reinterpret_cast<const float4*>(&x[base]);
        const float4 c = *reinterpret_cast<const float4*>(&x[base + 4]);
        uint4 o;
        o.x = (unsigned)(unsigned short)rne_bf16(a.x) | ((unsigned)(unsigned short)rne_bf16(a.y) << 16);
        o.y = (unsigned)(unsigned short)rne_bf16(a.z) | ((unsigned)(unsigned short)rne_bf16(a.w) << 16);
        o.z = (unsigned)(unsigned short)rne_bf16(c.x) | ((unsigned)(unsigned short)rne_bf16(c.y) << 16);
        o.w = (unsigned)(unsigned short)rne_bf16(c.z) | ((unsigned)(unsigned short)rne_bf16(c.w) << 16);
        *reinterpret_cast<uint4*>(&xb[base]) = o;
    } else {
        int idx = (b - 1024) * 256 + threadIdx.x;   // 65536 total
        int layer = idx >> 15;
        int rem = idx & 32767;
        int c = rem >> 8, k = rem & 255;
        const float* Wl = layer ? W2l : W1l;
        const float* Wr = layer ? W2r : W1r;
        float v = (k < 128) ? Wl[c * 128 + k] : Wr[c * 128 + (k - 128)];
        short* Bc = layer ? Bc2 : Bc1;
        Bc[c * 256 + k] = rne_bf16(v);
    }
}

// ---------- int degree histogram ----------
__global__ __launch_bounds__(256) void degi_kernel(const int* __restrict__ dst,
                                                   int* __restrict__ degi, int E) {
    int e = blockIdx.x * 256 + threadIdx.x;
    if (e < E) atomicAdd(&degi[dst[e]], 1);
}

// ---------- exclusive prefix scan of degi -> rowptr, plus invdeg ----------
__global__ __launch_bounds__(1024) void scan_kernel(const int* __restrict__ degi,
                                                    int* __restrict__ rowptr,
                                                    float* __restrict__ invdeg, int N) {
    __shared__ int part[1024];
    int tid = threadIdx.x;
    int base = tid * 16;
    int loc[16];
    int s = 0;
#pragma unroll
    for (int i = 0; i < 16; i++) {
        int d = degi[base + i];
        loc[i] = s; s += d;
        invdeg[base + i] = 1.0f / fmaxf((float)d, 1.0f);
    }
    part[tid] = s;
    __syncthreads();
    for (int off = 1; off < 1024; off <<= 1) {
        int t = (tid >= off) ? part[tid - off] : 0;
        __syncthreads();
        if (tid >= off) part[tid] += t;
        __syncthreads();
    }
    int prefix = part[tid] - s;  // exclusive
#pragma unroll
    for (int i = 0; i < 16; i++) rowptr[base + i] = prefix + loc[i];
    if (tid == 1023) rowptr[N] = prefix + s;
}

// ---------- CSR fill ----------
__global__ __launch_bounds__(256) void fill_kernel(const int* __restrict__ src,
                                                   const int* __restrict__ dst,
                                                   const int* __restrict__ rowptr,
                                                   int* __restrict__ cursor,
                                                   int* __restrict__ csr_src, int E) {
    int e = blockIdx.x * 256 + threadIdx.x;
    if (e < E) {
        int d = dst[e];
        int pos = atomicAdd(&cursor[d], 1);
        csr_src[rowptr[d] + pos] = src[e];
    }
}

// ---------- fused gather + MFMA SAGE (+ optional score epilogue) ----------
// Block: 256 thr = 4 waves, 32 rows x 128 cols. Grid N/32.
// Phase 1: each wave gather-means 8 rows of Asrc into LDS (bf16, XOR-swizzled).
// Phase 2: MFMA over K=256 ([agg | root] @ Bc^T), bias, relu/store.
// Phase 3 (score): per-row dot(h,aux) & |h|^2 via shfl+LDS reduce -> sbuf/wbuf.
__global__ __launch_bounds__(256) void sage_fused_kernel(const short* __restrict__ Asrc,
                                                         const short* __restrict__ Bc,
                                                         const float* __restrict__ bias,
                                                         const int* __restrict__ rowptr,
                                                         const int* __restrict__ csr_src,
                                                         const float* __restrict__ invdeg,
                                                         const float* __restrict__ aux,
                                                         short* __restrict__ outb,
                                                         float* __restrict__ outf,
                                                         float* __restrict__ sbuf,
                                                         float* __restrict__ wbuf,
                                                         int relu, int score) {
    __shared__ short aggl[32 * 128];       // 8 KB, XOR-swizzled rows
    __shared__ float sdot[32][2];
    __shared__ float snrm[32][2];
    __shared__ float an_s;

    int lane = threadIdx.x & 63;
    int wid = threadIdx.x >> 6;
    int row0 = blockIdx.x * 32;

    // aux norm (wave 0 only, score only)
    if (score && wid == 0) {
        float2 av = *reinterpret_cast<const float2*>(&aux[lane * 2]);
        float na = av.x * av.x + av.y * av.y;
        for (int m = 1; m < 64; m <<= 1) na += __shfl_xor(na, m);
        if (lane == 0) an_s = fmaxf(sqrtf(na), 1e-8f);
    }

    // phase 1: gather-mean 8 rows per wave into LDS
    for (int rr = 0; rr < 8; rr++) {
        int r = wid * 8 + rr;
        int node = row0 + r;
        int beg = rowptr[node], end = rowptr[node + 1];
        float ax = 0.0f, ay = 0.0f;
        for (int j = beg; j < end; j++) {
            int s = csr_src[j];
            unsigned v = *reinterpret_cast<const unsigned*>(&Asrc[(size_t)s * D + lane * 2]);
            ax += bf16_to_f(v & 0xffffu);
            ay += bf16_to_f(v >> 16);
        }
        float inv = invdeg[node];
        unsigned o = (unsigned)(unsigned short)rne_bf16(ax * inv) |
                     ((unsigned)(unsigned short)rne_bf16(ay * inv) << 16);
        int byte = (r * 256 + lane * 4) ^ ((r & 7) << 4);
        *reinterpret_cast<unsigned*>(reinterpret_cast<char*>(aggl) + byte) = o;
    }
    __syncthreads();

    // phase 2: MFMA
    int arow_l = (wid & 1) * 16 + (lane & 15);
    int colq = lane & 15;
    int koff = (lane >> 4) * 8;
    int colbase = (wid >> 1) * 64;

    f32x4 acc[4];
#pragma unroll
    for (int t = 0; t < 4; t++) acc[t] = (f32x4){0.0f, 0.0f, 0.0f, 0.0f};

#pragma unroll
    for (int kc = 0; kc < 8; kc++) {
        int k = (kc & 3) * 32 + koff;
        bf16x8 a;
        if (kc < 4) {
            int byte = (arow_l * 256 + k * 2) ^ ((arow_l & 7) << 4);
            a = *reinterpret_cast<const bf16x8*>(reinterpret_cast<const char*>(aggl) + byte);
        } else {
            a = *reinterpret_cast<const bf16x8*>(&Asrc[(size_t)(row0 + arow_l) * D + k]);
        }
#pragma unroll
        for (int t = 0; t < 4; t++) {
            int col = colbase + t * 16 + colq;
            bf16x8 b = *reinterpret_cast<const bf16x8*>(&Bc[(size_t)col * 256 + kc * 32 + koff]);
            acc[t] = __builtin_amdgcn_mfma_f32_16x16x32_bf16(a, b, acc[t], 0, 0, 0);
        }
    }

    // epilogue: bias + relu + store (+ score partials)
    int rbase_l = (wid & 1) * 16 + (lane >> 4) * 4;
    float dotp[4] = {0.0f, 0.0f, 0.0f, 0.0f};
    float nrmp[4] = {0.0f, 0.0f, 0.0f, 0.0f};
#pragma unroll
    for (int t = 0; t < 4; t++) {
        int col = colbase + t * 16 + colq;
        float bv = bias[col];
        float av = score ? aux[col] : 0.0f;
#pragma unroll
        for (int r = 0; r < 4; r++) {
            float v = acc[t][r] + bv;
            if (relu) v = fmaxf(v, 0.0f);
            if (outf) outf[(size_t)(row0 + rbase_l + r) * D + col] = v;
            else outb[(size_t)(row0 + rbase_l + r) * D + col] = rne_bf16(v);
            dotp[r] += v * av;
            nrmp[r] += v * v;
        }
    }

    if (score) {
        // reduce across the 16 lanes of each quarter-wave (cols within this wave's half)
#pragma unroll
        for (int m = 1; m < 16; m <<= 1) {
#pragma unroll
            for (int r = 0; r < 4; r++) {
                dotp[r] += __shfl_xor(dotp[r], m);
                nrmp[r] += __shfl_xor(nrmp[r], m);
            }
        }
        if ((lane & 15) == 0) {
#pragma unroll
            for (int r = 0; r < 4; r++) {
                sdot[rbase_l + r][wid >> 1] = dotp[r];
                snrm[rbase_l + r][wid >> 1] = nrmp[r];
            }
        }
        __syncthreads();
        int tid = threadIdx.x;
        if (tid < 32) {
            float dot = sdot[tid][0] + sdot[tid][1];
            float nh = snrm[tid][0] + snrm[tid][1];
            float hn = fmaxf(sqrtf(nh), 1e-8f);
            float sc = dot / (hn * an_s);
            sbuf[row0 + tid] = sc;
            wbuf[row0 + tid] = expf(-sc * sc);
        }
    }
}

// ---------- moments: 512 threads, 8 waves x 8 rows, LDS cross-wave reduce ----------
__global__ __launch_bounds__(512) void moments_kernel(const float* __restrict__ h,
                                                      const float* __restrict__ sbuf,
                                                      const float* __restrict__ wbuf,
                                                      float* __restrict__ M,
                                                      float* __restrict__ mden, int N) {
    __shared__ float lds[8 * KTERMS * D];     // 64 KB
    __shared__ float ldsm[8 * KTERMS];
    int tid = threadIdx.x;
    int w = tid >> 6, lane = tid & 63;
    int j0 = blockIdx.x * 64 + w * 8;

    float2 acc[KTERMS];
    float macc[KTERMS];
#pragma unroll
    for (int k = 0; k < KTERMS; k++) { acc[k] = make_float2(0.0f, 0.0f); macc[k] = 0.0f; }

    for (int j = j0; j < j0 + 8; j++) {
        float sj = sbuf[j];
        float wj = wbuf[j];
        float2 hv = *reinterpret_cast<const float2*>(&h[(size_t)j * D + lane * 2]);
        float coef = wj;
#pragma unroll
        for (int k = 0; k < KTERMS; k++) {
            acc[k].x += coef * hv.x;
            acc[k].y += coef * hv.y;
            macc[k] += coef;
            coef *= sj;
        }
    }

#pragma unroll
    for (int k = 0; k < KTERMS; k++) {
        lds[(w * KTERMS + k) * D + lane * 2]     = acc[k].x;
        lds[(w * KTERMS + k) * D + lane * 2 + 1] = acc[k].y;
    }
    if (lane == 0) {
#pragma unroll
        for (int k = 0; k < KTERMS; k++) ldsm[w * KTERMS + k] = macc[k];
    }
    __syncthreads();

    for (int e = tid; e < KTERMS * D; e += 512) {
        float s = 0.0f;
#pragma unroll
        for (int ww = 0; ww < 8; ww++) s += lds[ww * KTERMS * D + e];
        atomicAdd(&M[e], s);
    }
    if (tid < KTERMS) {
        float s = 0.0f;
#pragma unroll
        for (int ww = 0; ww < 8; ww++) s += ldsm[ww * KTERMS + tid];
        atomicAdd(&mden[tid], s);
    }
}

// ---------- fused z + classifier: out[n][c] = [h,z]@Wc^T + bc ----------
// Block: 128 threads (2 waves), 16 nodes. Thread tid owns feature col tid.
__global__ __launch_bounds__(128) void zcls_kernel(const float* __restrict__ M,
                                                   const float* __restrict__ mden,
                                                   const float* __restrict__ sbuf,
                                                   const float* __restrict__ h,
                                                   const float* __restrict__ Wc,
                                                   const float* __restrict__ bc,
                                                   float* __restrict__ out, int N) {
    const float A[KTERMS] = {1.0f, 2.0f, 2.0f, 1.3333334f, 0.6666667f, 0.26666668f,
                             0.08888889f, 0.025396826f, 0.0063492064f, 0.0014109347f,
                             2.8218695e-4f, 5.1306718e-5f, 8.5511196e-6f, 1.3155569e-6f,
                             1.8793670e-7f, 2.5058226e-8f};
    __shared__ float Ml[KTERMS * D];
    __shared__ float ml[KTERMS];
    __shared__ float wls[10 * 256];
    __shared__ float red[10][2];
    int tid = threadIdx.x;
    int lane = tid & 63, w = tid >> 6;
#pragma unroll
    for (int k = 0; k < KTERMS; k++) Ml[k * D + tid] = M[k * D + tid];
    if (tid < KTERMS) ml[tid] = mden[tid];
    for (int e = tid; e < 10 * 256; e += 128) wls[e] = Wc[e];
    __syncthreads();

    int n0 = blockIdx.x * 16;
    for (int n = n0; n < n0 + 16; n++) {
        float si = sbuf[n];
        float num = 0.0f, den = 0.0f, p = 1.0f;
#pragma unroll
        for (int k = 0; k < KTERMS; k++) {
            float ck = A[k] * p;
            num += ck * Ml[k * D + tid];
            den += ck * ml[k];
            p *= si;
        }
        float zc = num / den;
        float hc = h[(size_t)n * D + tid];

        float part[10];
#pragma unroll
        for (int c = 0; c < 10; c++)
            part[c] = hc * wls[c * 256 + tid] + zc * wls[c * 256 + 128 + tid];
#pragma unroll
        for (int m = 1; m < 64; m <<= 1) {
#pragma unroll
            for (int c = 0; c < 10; c++) part[c] += __shfl_xor(part[c], m);
        }
        if (lane == 0) {
#pragma unroll
            for (int c = 0; c < 10; c++) red[c][w] = part[c];
        }
        __syncthreads();
        if (tid < 10) out[(size_t)n * 10 + tid] = red[tid][0] + red[tid][1] + bc[tid];
        __syncthreads();
    }
}

extern "C" void kernel_launch(void* const* d_in, const int* in_sizes, int n_in,
                              void* d_out, int out_size, void* d_ws, size_t ws_size,
                              hipStream_t stream) {
    const float* x   = (const float*)d_in[0];
    const int*   ei  = (const int*)d_in[1];
    const float* W1l = (const float*)d_in[2];
    const float* b1l = (const float*)d_in[3];
    const float* W1r = (const float*)d_in[4];
    const float* W2l = (const float*)d_in[5];
    const float* b2l = (const float*)d_in[6];
    const float* W2r = (const float*)d_in[7];
    const float* aux = (const float*)d_in[8];
    const float* Wc  = (const float*)d_in[9];
    const float* bc  = (const float*)d_in[10];
    float* out = (float*)d_out;

    const int N = in_sizes[0] / D;
    const int E = in_sizes[1] / 2;
    const int* srcArr = ei;
    const int* dstArr = ei + E;
    const size_t ND = (size_t)N * D;

    // ---- workspace carve-up ----
    int* ip = (int*)d_ws;
    int* degi    = ip; ip += N;
    int* cursor  = ip; ip += N;
    int* rowptr  = ip; ip += N + 1;
    int* csr_src = ip; ip += E;
    uintptr_t up = ((uintptr_t)ip + 15) & ~(uintptr_t)15;
    short* sp = (short*)up;
    short* xb   = sp; sp += ND;
    short* h1b  = sp; sp += ND;
    short* Bc1  = sp; sp += 128 * 256;
    short* Bc2  = sp; sp += 128 * 256;
    up = ((uintptr_t)sp + 15) & ~(uintptr_t)15;
    float* p = (float*)up;
    float* invdeg = p; p += N;
    float* sbuf   = p; p += N;
    float* wbuf   = p; p += N;
    float* M      = p; p += KTERMS * D;
    float* mden   = p; p += KTERMS;
    float* h2     = p; p += ND;

    hipMemsetAsync(degi, 0, (size_t)(2 * N) * sizeof(int), stream);
    hipMemsetAsync(M, 0, (size_t)(KTERMS * D + KTERMS) * sizeof(float), stream);

    // prep: x->bf16 convert + weight concat
    prep_kernel<<<1280, 256, 0, stream>>>(x, xb, W1l, W1r, W2l, W2r, Bc1, Bc2);

    // build CSR (sorted by dst)
    degi_kernel<<<(E + 255) / 256, 256, 0, stream>>>(dstArr, degi, E);
    scan_kernel<<<1, 1024, 0, stream>>>(degi, rowptr, invdeg, N);
    fill_kernel<<<(E + 255) / 256, 256, 0, stream>>>(srcArr, dstArr, rowptr, cursor, csr_src, E);

    // layer 1: h1b = relu([gather(xb)|xb] @ Bc1^T + b1l)
    sage_fused_kernel<<<N / 32, 256, 0, stream>>>(xb, Bc1, b1l, rowptr, csr_src, invdeg,
                                                  aux, h1b, nullptr, nullptr, nullptr, 1, 0);
    // layer 2: h2 = [gather(h1b)|h1b] @ Bc2^T + b2l, + score epilogue
    sage_fused_kernel<<<N / 32, 256, 0, stream>>>(h1b, Bc2, b2l, rowptr, csr_src, invdeg,
                                                  aux, nullptr, h2, sbuf, wbuf, 0, 1);

    // Taylor moments
    moments_kernel<<<N / 64, 512, 0, stream>>>(h2, sbuf, wbuf, M, mden, N);

    // fused z + classifier
    zcls_kernel<<<N / 16, 128, 0, stream>>>(M, mden, sbuf, h2, Wc, bc, out, N);
}

// Round 8
// 160.274 us; speedup vs baseline: 1.5058x; 1.5058x over previous
//
#include <hip/hip_runtime.h>
#include <hip/hip_bf16.h>

#define D 128
#define KTERMS 16

typedef __attribute__((ext_vector_type(8))) short bf16x8;
typedef __attribute__((ext_vector_type(4))) float f32x4;

__device__ inline short rne_bf16(float f) {
    union { float f; unsigned u; } v; v.f = f;
    unsigned r = (v.u + 0x7fffu + ((v.u >> 16) & 1u)) >> 16;
    return (short)r;
}
__device__ inline float bf16_to_f(unsigned s) {
    union { unsigned u; float f; } v; v.u = s << 16;
    return v.f;
}
__device__ inline unsigned pk2(float a, float b) {
    return (unsigned)(unsigned short)rne_bf16(a) | ((unsigned)(unsigned short)rne_bf16(b) << 16);
}

// ---------- prep: blocks [0,1024) convert x->bf16; blocks [1024,1280) build concat weights ----------
__global__ __launch_bounds__(256) void prep_kernel(const float* __restrict__ x,
                                                   short* __restrict__ xb,
                                                   const float* __restrict__ W1l,
                                                   const float* __restrict__ W1r,
                                                   const float* __restrict__ W2l,
                                                   const float* __restrict__ W2r,
                                                   short* __restrict__ Bc1,
                                                   short* __restrict__ Bc2) {
    int b = blockIdx.x;
    if (b < 1024) {
        int base = (b * 256 + threadIdx.x) * 8;
        const float4 a = *reinterpret_cast<const float4*>(&x[base]);
        const float4 c = *reinterpret_cast<const float4*>(&x[base + 4]);
        uint4 o;
        o.x = pk2(a.x, a.y);
        o.y = pk2(a.z, a.w);
        o.z = pk2(c.x, c.y);
        o.w = pk2(c.z, c.w);
        *reinterpret_cast<uint4*>(&xb[base]) = o;
    } else {
        int idx = (b - 1024) * 256 + threadIdx.x;   // 65536 total
        int layer = idx >> 15;
        int rem = idx & 32767;
        int c = rem >> 8, k = rem & 255;
        const float* Wl = layer ? W2l : W1l;
        const float* Wr = layer ? W2r : W1r;
        float v = (k < 128) ? Wl[c * 128 + k] : Wr[c * 128 + (k - 128)];
        short* Bc = layer ? Bc2 : Bc1;
        Bc[c * 256 + k] = rne_bf16(v);
    }
}

// ---------- int degree histogram ----------
__global__ __launch_bounds__(256) void degi_kernel(const int* __restrict__ dst,
                                                   int* __restrict__ degi, int E) {
    int e = blockIdx.x * 256 + threadIdx.x;
    if (e < E) atomicAdd(&degi[dst[e]], 1);
}

// ---------- exclusive prefix scan of degi -> rowptr, plus invdeg ----------
__global__ __launch_bounds__(1024) void scan_kernel(const int* __restrict__ degi,
                                                    int* __restrict__ rowptr,
                                                    float* __restrict__ invdeg, int N) {
    __shared__ int part[1024];
    int tid = threadIdx.x;
    int base = tid * 16;
    int loc[16];
    int s = 0;
#pragma unroll
    for (int i = 0; i < 16; i++) {
        int d = degi[base + i];
        loc[i] = s; s += d;
        invdeg[base + i] = 1.0f / fmaxf((float)d, 1.0f);
    }
    part[tid] = s;
    __syncthreads();
    for (int off = 1; off < 1024; off <<= 1) {
        int t = (tid >= off) ? part[tid - off] : 0;
        __syncthreads();
        if (tid >= off) part[tid] += t;
        __syncthreads();
    }
    int prefix = part[tid] - s;  // exclusive
#pragma unroll
    for (int i = 0; i < 16; i++) rowptr[base + i] = prefix + loc[i];
    if (tid == 1023) rowptr[N] = prefix + s;
}

// ---------- CSR fill ----------
__global__ __launch_bounds__(256) void fill_kernel(const int* __restrict__ src,
                                                   const int* __restrict__ dst,
                                                   const int* __restrict__ rowptr,
                                                   int* __restrict__ cursor,
                                                   int* __restrict__ csr_src, int E) {
    int e = blockIdx.x * 256 + threadIdx.x;
    if (e < E) {
        int d = dst[e];
        int pos = atomicAdd(&cursor[d], 1);
        csr_src[rowptr[d] + pos] = src[e];
    }
}

// ---------- gather-mean v3: 16-lane subgroups, 4 nodes/wave, 16B row segments ----------
// Block 256 thr = 4 waves = 16 nodes. Grid N/16.
__global__ __launch_bounds__(256) void gatherb_kernel(const short* __restrict__ xin,
                                                      const int* __restrict__ rowptr,
                                                      const int* __restrict__ csr_src,
                                                      const float* __restrict__ invdeg,
                                                      short* __restrict__ aggb, int N) {
    int lane = threadIdx.x & 63;
    int wid = threadIdx.x >> 6;
    int sub = lane >> 4;       // subgroup 0..3 -> node
    int sl = lane & 15;        // sub-lane: 8 bf16 features each
    int node = (blockIdx.x * 4 + wid) * 4 + sub;
    if (node >= N) return;
    int beg = rowptr[node], end = rowptr[node + 1];
    float acc[8] = {0.0f, 0.0f, 0.0f, 0.0f, 0.0f, 0.0f, 0.0f, 0.0f};
    for (int j = beg; j < end; j++) {
        int s = csr_src[j];
        const uint4 v = *reinterpret_cast<const uint4*>(&xin[(size_t)s * D + sl * 8]);
        acc[0] += bf16_to_f(v.x & 0xffffu);
        acc[1] += bf16_to_f(v.x >> 16);
        acc[2] += bf16_to_f(v.y & 0xffffu);
        acc[3] += bf16_to_f(v.y >> 16);
        acc[4] += bf16_to_f(v.z & 0xffffu);
        acc[5] += bf16_to_f(v.z >> 16);
        acc[6] += bf16_to_f(v.w & 0xffffu);
        acc[7] += bf16_to_f(v.w >> 16);
    }
    float inv = invdeg[node];
    uint4 o;
    o.x = pk2(acc[0] * inv, acc[1] * inv);
    o.y = pk2(acc[2] * inv, acc[3] * inv);
    o.z = pk2(acc[4] * inv, acc[5] * inv);
    o.w = pk2(acc[6] * inv, acc[7] * inv);
    *reinterpret_cast<uint4*>(&aggb[(size_t)node * D + sl * 8]) = o;
}

// ---------- MFMA SAGE (+ optional score epilogue) ----------
// Block: 256 thr = 4 waves (2 row-half x 2 col-half), 32 rows x 128 cols. Grid N/32.
__global__ __launch_bounds__(256) void sage_mfma_kernel(const short* __restrict__ Aagg,
                                                        const short* __restrict__ Aroot,
                                                        const short* __restrict__ Bc,
                                                        const float* __restrict__ bias,
                                                        const float* __restrict__ aux,
                                                        short* __restrict__ outb,
                                                        float* __restrict__ outf,
                                                        float* __restrict__ sbuf,
                                                        float* __restrict__ wbuf,
                                                        int relu, int score) {
    __shared__ float sdot[32][2];
    __shared__ float snrm[32][2];
    __shared__ float an_s;

    int lane = threadIdx.x & 63;
    int wid = threadIdx.x >> 6;
    int row0 = blockIdx.x * 32;

    if (score && wid == 0) {
        float2 av = *reinterpret_cast<const float2*>(&aux[lane * 2]);
        float na = av.x * av.x + av.y * av.y;
        for (int m = 1; m < 64; m <<= 1) na += __shfl_xor(na, m);
        if (lane == 0) an_s = fmaxf(sqrtf(na), 1e-8f);
    }

    int arow = row0 + (wid & 1) * 16 + (lane & 15);
    int colq = lane & 15;
    int koff = (lane >> 4) * 8;
    int colbase = (wid >> 1) * 64;

    f32x4 acc[4];
#pragma unroll
    for (int t = 0; t < 4; t++) acc[t] = (f32x4){0.0f, 0.0f, 0.0f, 0.0f};

#pragma unroll
    for (int kc = 0; kc < 8; kc++) {
        const short* Asrc = (kc < 4) ? Aagg : Aroot;
        int k = (kc & 3) * 32 + koff;
        bf16x8 a = *reinterpret_cast<const bf16x8*>(&Asrc[(size_t)arow * D + k]);
#pragma unroll
        for (int t = 0; t < 4; t++) {
            int col = colbase + t * 16 + colq;
            bf16x8 b = *reinterpret_cast<const bf16x8*>(&Bc[(size_t)col * 256 + kc * 32 + koff]);
            acc[t] = __builtin_amdgcn_mfma_f32_16x16x32_bf16(a, b, acc[t], 0, 0, 0);
        }
    }

    int rbase_l = (wid & 1) * 16 + (lane >> 4) * 4;
    float dotp[4] = {0.0f, 0.0f, 0.0f, 0.0f};
    float nrmp[4] = {0.0f, 0.0f, 0.0f, 0.0f};
#pragma unroll
    for (int t = 0; t < 4; t++) {
        int col = colbase + t * 16 + colq;
        float bv = bias[col];
        float av = score ? aux[col] : 0.0f;
#pragma unroll
        for (int r = 0; r < 4; r++) {
            float v = acc[t][r] + bv;
            if (relu) v = fmaxf(v, 0.0f);
            if (outf) outf[(size_t)(row0 + rbase_l + r) * D + col] = v;
            else outb[(size_t)(row0 + rbase_l + r) * D + col] = rne_bf16(v);
            dotp[r] += v * av;
            nrmp[r] += v * v;
        }
    }

    if (score) {
#pragma unroll
        for (int m = 1; m < 16; m <<= 1) {
#pragma unroll
            for (int r = 0; r < 4; r++) {
                dotp[r] += __shfl_xor(dotp[r], m);
                nrmp[r] += __shfl_xor(nrmp[r], m);
            }
        }
        if ((lane & 15) == 0) {
#pragma unroll
            for (int r = 0; r < 4; r++) {
                sdot[rbase_l + r][wid >> 1] = dotp[r];
                snrm[rbase_l + r][wid >> 1] = nrmp[r];
            }
        }
        __syncthreads();
        int tid = threadIdx.x;
        if (tid < 32) {
            float dot = sdot[tid][0] + sdot[tid][1];
            float nh = snrm[tid][0] + snrm[tid][1];
            float hn = fmaxf(sqrtf(nh), 1e-8f);
            float sc = dot / (hn * an_s);
            sbuf[row0 + tid] = sc;
            wbuf[row0 + tid] = expf(-sc * sc);
        }
    }
}

// ---------- moments: 512 threads, 8 waves x 8 rows, LDS cross-wave reduce ----------
__global__ __launch_bounds__(512) void moments_kernel(const float* __restrict__ h,
                                                      const float* __restrict__ sbuf,
                                                      const float* __restrict__ wbuf,
                                                      float* __restrict__ M,
                                                      float* __restrict__ mden, int N) {
    __shared__ float lds[8 * KTERMS * D];     // 64 KB
    __shared__ float ldsm[8 * KTERMS];
    int tid = threadIdx.x;
    int w = tid >> 6, lane = tid & 63;
    int j0 = blockIdx.x * 64 + w * 8;

    float2 acc[KTERMS];
    float macc[KTERMS];
#pragma unroll
    for (int k = 0; k < KTERMS; k++) { acc[k] = make_float2(0.0f, 0.0f); macc[k] = 0.0f; }

    for (int j = j0; j < j0 + 8; j++) {
        float sj = sbuf[j];
        float wj = wbuf[j];
        float2 hv = *reinterpret_cast<const float2*>(&h[(size_t)j * D + lane * 2]);
        float coef = wj;
#pragma unroll
        for (int k = 0; k < KTERMS; k++) {
            acc[k].x += coef * hv.x;
            acc[k].y += coef * hv.y;
            macc[k] += coef;
            coef *= sj;
        }
    }

#pragma unroll
    for (int k = 0; k < KTERMS; k++) {
        lds[(w * KTERMS + k) * D + lane * 2]     = acc[k].x;
        lds[(w * KTERMS + k) * D + lane * 2 + 1] = acc[k].y;
    }
    if (lane == 0) {
#pragma unroll
        for (int k = 0; k < KTERMS; k++) ldsm[w * KTERMS + k] = macc[k];
    }
    __syncthreads();

    for (int e = tid; e < KTERMS * D; e += 512) {
        float s = 0.0f;
#pragma unroll
        for (int ww = 0; ww < 8; ww++) s += lds[ww * KTERMS * D + e];
        atomicAdd(&M[e], s);
    }
    if (tid < KTERMS) {
        float s = 0.0f;
#pragma unroll
        for (int ww = 0; ww < 8; ww++) s += ldsm[ww * KTERMS + tid];
        atomicAdd(&mden[tid], s);
    }
}

// ---------- fused z + classifier: out[n][c] = [h,z]@Wc^T + bc ----------
__global__ __launch_bounds__(128) void zcls_kernel(const float* __restrict__ M,
                                                   const float* __restrict__ mden,
                                                   const float* __restrict__ sbuf,
                                                   const float* __restrict__ h,
                                                   const float* __restrict__ Wc,
                                                   const float* __restrict__ bc,
                                                   float* __restrict__ out, int N) {
    const float A[KTERMS] = {1.0f, 2.0f, 2.0f, 1.3333334f, 0.6666667f, 0.26666668f,
                             0.08888889f, 0.025396826f, 0.0063492064f, 0.0014109347f,
                             2.8218695e-4f, 5.1306718e-5f, 8.5511196e-6f, 1.3155569e-6f,
                             1.8793670e-7f, 2.5058226e-8f};
    __shared__ float Ml[KTERMS * D];
    __shared__ float ml[KTERMS];
    __shared__ float wls[10 * 256];
    __shared__ float red[10][2];
    int tid = threadIdx.x;
    int lane = tid & 63, w = tid >> 6;
#pragma unroll
    for (int k = 0; k < KTERMS; k++) Ml[k * D + tid] = M[k * D + tid];
    if (tid < KTERMS) ml[tid] = mden[tid];
    for (int e = tid; e < 10 * 256; e += 128) wls[e] = Wc[e];
    __syncthreads();

    int n0 = blockIdx.x * 16;
    for (int n = n0; n < n0 + 16; n++) {
        float si = sbuf[n];
        float num = 0.0f, den = 0.0f, p = 1.0f;
#pragma unroll
        for (int k = 0; k < KTERMS; k++) {
            float ck = A[k] * p;
            num += ck * Ml[k * D + tid];
            den += ck * ml[k];
            p *= si;
        }
        float zc = num / den;
        float hc = h[(size_t)n * D + tid];

        float part[10];
#pragma unroll
        for (int c = 0; c < 10; c++)
            part[c] = hc * wls[c * 256 + tid] + zc * wls[c * 256 + 128 + tid];
#pragma unroll
        for (int m = 1; m < 64; m <<= 1) {
#pragma unroll
            for (int c = 0; c < 10; c++) part[c] += __shfl_xor(part[c], m);
        }
        if (lane == 0) {
#pragma unroll
            for (int c = 0; c < 10; c++) red[c][w] = part[c];
        }
        __syncthreads();
        if (tid < 10) out[(size_t)n * 10 + tid] = red[tid][0] + red[tid][1] + bc[tid];
        __syncthreads();
    }
}

extern "C" void kernel_launch(void* const* d_in, const int* in_sizes, int n_in,
                              void* d_out, int out_size, void* d_ws, size_t ws_size,
                              hipStream_t stream) {
    const float* x   = (const float*)d_in[0];
    const int*   ei  = (const int*)d_in[1];
    const float* W1l = (const float*)d_in[2];
    const float* b1l = (const float*)d_in[3];
    const float* W1r = (const float*)d_in[4];
    const float* W2l = (const float*)d_in[5];
    const float* b2l = (const float*)d_in[6];
    const float* W2r = (const float*)d_in[7];
    const float* aux = (const float*)d_in[8];
    const float* Wc  = (const float*)d_in[9];
    const float* bc  = (const float*)d_in[10];
    float* out = (float*)d_out;

    const int N = in_sizes[0] / D;
    const int E = in_sizes[1] / 2;
    const int* srcArr = ei;
    const int* dstArr = ei + E;
    const size_t ND = (size_t)N * D;

    // ---- workspace carve-up ----
    int* ip = (int*)d_ws;
    int* degi    = ip; ip += N;
    int* cursor  = ip; ip += N;
    int* rowptr  = ip; ip += N + 1;
    int* csr_src = ip; ip += E;
    uintptr_t up = ((uintptr_t)ip + 15) & ~(uintptr_t)15;
    short* sp = (short*)up;
    short* xb   = sp; sp += ND;
    short* aggb = sp; sp += ND;
    short* h1b  = sp; sp += ND;
    short* Bc1  = sp; sp += 128 * 256;
    short* Bc2  = sp; sp += 128 * 256;
    up = ((uintptr_t)sp + 15) & ~(uintptr_t)15;
    float* p = (float*)up;
    float* invdeg = p; p += N;
    float* sbuf   = p; p += N;
    float* wbuf   = p; p += N;
    float* M      = p; p += KTERMS * D;
    float* mden   = p; p += KTERMS;
    float* h2     = p; p += ND;

    hipMemsetAsync(degi, 0, (size_t)(2 * N) * sizeof(int), stream);
    hipMemsetAsync(M, 0, (size_t)(KTERMS * D + KTERMS) * sizeof(float), stream);

    // prep: x->bf16 convert + weight concat
    prep_kernel<<<1280, 256, 0, stream>>>(x, xb, W1l, W1r, W2l, W2r, Bc1, Bc2);

    // build CSR (sorted by dst)
    degi_kernel<<<(E + 255) / 256, 256, 0, stream>>>(dstArr, degi, E);
    scan_kernel<<<1, 1024, 0, stream>>>(degi, rowptr, invdeg, N);
    fill_kernel<<<(E + 255) / 256, 256, 0, stream>>>(srcArr, dstArr, rowptr, cursor, csr_src, E);

    // layer 1: h1b = relu([gather(xb)|xb] @ Bc1^T + b1l)
    gatherb_kernel<<<N / 16, 256, 0, stream>>>(xb, rowptr, csr_src, invdeg, aggb, N);
    sage_mfma_kernel<<<N / 32, 256, 0, stream>>>(aggb, xb, Bc1, b1l, aux,
                                                 h1b, nullptr, nullptr, nullptr, 1, 0);
    // layer 2: h2 = [gather(h1b)|h1b] @ Bc2^T + b2l, + score epilogue
    gatherb_kernel<<<N / 16, 256, 0, stream>>>(h1b, rowptr, csr_src, invdeg, aggb, N);
    sage_mfma_kernel<<<N / 32, 256, 0, stream>>>(aggb, h1b, Bc2, b2l, aux,
                                                 nullptr, h2, sbuf, wbuf, 0, 1);

    // Taylor moments
    moments_kernel<<<N / 64, 512, 0, stream>>>(h2, sbuf, wbuf, M, mden, N);

    // fused z + classifier
    zcls_kernel<<<N / 16, 128, 0, stream>>>(M, mden, sbuf, h2, Wc, bc, out, N);
}

// Round 9
// 134.094 us; speedup vs baseline: 1.7998x; 1.1952x over previous
//
#include <hip/hip_runtime.h>
#include <hip/hip_bf16.h>

#define D 128
#define KTERMS 16

typedef __attribute__((ext_vector_type(8))) short bf16x8;
typedef __attribute__((ext_vector_type(4))) float f32x4;

__device__ inline short rne_bf16(float f) {
    union { float f; unsigned u; } v; v.f = f;
    unsigned r = (v.u + 0x7fffu + ((v.u >> 16) & 1u)) >> 16;
    return (short)r;
}
__device__ inline float bf16_to_f(unsigned s) {
    union { unsigned u; float f; } v; v.u = s << 16;
    return v.f;
}
__device__ inline unsigned pk2(float a, float b) {
    return (unsigned)(unsigned short)rne_bf16(a) | ((unsigned)(unsigned short)rne_bf16(b) << 16);
}
__device__ inline void addv(float* acc, uint4 v) {
    acc[0] += bf16_to_f(v.x & 0xffffu);
    acc[1] += bf16_to_f(v.x >> 16);
    acc[2] += bf16_to_f(v.y & 0xffffu);
    acc[3] += bf16_to_f(v.y >> 16);
    acc[4] += bf16_to_f(v.z & 0xffffu);
    acc[5] += bf16_to_f(v.z >> 16);
    acc[6] += bf16_to_f(v.w & 0xffffu);
    acc[7] += bf16_to_f(v.w >> 16);
}

// ---------- prep: cvt x->bf16 [0,1024) | concat weights [1024,1280) | zero degi+cursor [1280,1312) | zero M [1312] ----------
__global__ __launch_bounds__(256) void prep_kernel(const float* __restrict__ x,
                                                   short* __restrict__ xb,
                                                   const float* __restrict__ W1l,
                                                   const float* __restrict__ W1r,
                                                   const float* __restrict__ W2l,
                                                   const float* __restrict__ W2r,
                                                   short* __restrict__ Bc1,
                                                   short* __restrict__ Bc2,
                                                   int* __restrict__ zero_ints,   // degi+cursor, 2N ints
                                                   float* __restrict__ zero_f) {  // M+mden
    int b = blockIdx.x;
    int tid = threadIdx.x;
    if (b < 1024) {
        int base = (b * 256 + tid) * 8;
        const float4 a = *reinterpret_cast<const float4*>(&x[base]);
        const float4 c = *reinterpret_cast<const float4*>(&x[base + 4]);
        uint4 o;
        o.x = pk2(a.x, a.y);
        o.y = pk2(a.z, a.w);
        o.z = pk2(c.x, c.y);
        o.w = pk2(c.z, c.w);
        *reinterpret_cast<uint4*>(&xb[base]) = o;
    } else if (b < 1280) {
        int idx = (b - 1024) * 256 + tid;   // 65536 total
        int layer = idx >> 15;
        int rem = idx & 32767;
        int c = rem >> 8, k = rem & 255;
        const float* Wl = layer ? W2l : W1l;
        const float* Wr = layer ? W2r : W1r;
        float v = (k < 128) ? Wl[c * 128 + k] : Wr[c * 128 + (k - 128)];
        short* Bc = layer ? Bc2 : Bc1;
        Bc[c * 256 + k] = rne_bf16(v);
    } else if (b < 1312) {
        int idx = (b - 1280) * 256 + tid;   // 8192 int4 = 2N ints
        reinterpret_cast<int4*>(zero_ints)[idx] = make_int4(0, 0, 0, 0);
    } else {
        for (int e = tid; e < KTERMS * D + KTERMS; e += 256) zero_f[e] = 0.0f;
    }
}

// ---------- int degree histogram ----------
__global__ __launch_bounds__(256) void degi_kernel(const int* __restrict__ dst,
                                                   int* __restrict__ degi, int E) {
    int e = blockIdx.x * 256 + threadIdx.x;
    if (e < E) atomicAdd(&degi[dst[e]], 1);
}

// ---------- exclusive prefix scan of degi -> rowptr, plus invdeg ----------
__global__ __launch_bounds__(1024) void scan_kernel(const int* __restrict__ degi,
                                                    int* __restrict__ rowptr,
                                                    float* __restrict__ invdeg, int N) {
    __shared__ int part[1024];
    int tid = threadIdx.x;
    int base = tid * 16;
    int loc[16];
    int s = 0;
#pragma unroll
    for (int i = 0; i < 16; i++) {
        int d = degi[base + i];
        loc[i] = s; s += d;
        invdeg[base + i] = 1.0f / fmaxf((float)d, 1.0f);
    }
    part[tid] = s;
    __syncthreads();
    for (int off = 1; off < 1024; off <<= 1) {
        int t = (tid >= off) ? part[tid - off] : 0;
        __syncthreads();
        if (tid >= off) part[tid] += t;
        __syncthreads();
    }
    int prefix = part[tid] - s;  // exclusive
#pragma unroll
    for (int i = 0; i < 16; i++) rowptr[base + i] = prefix + loc[i];
    if (tid == 1023) rowptr[N] = prefix + s;
}

// ---------- CSR fill ----------
__global__ __launch_bounds__(256) void fill_kernel(const int* __restrict__ src,
                                                   const int* __restrict__ dst,
                                                   const int* __restrict__ rowptr,
                                                   int* __restrict__ cursor,
                                                   int* __restrict__ csr_src, int E) {
    int e = blockIdx.x * 256 + threadIdx.x;
    if (e < E) {
        int d = dst[e];
        int pos = atomicAdd(&cursor[d], 1);
        csr_src[rowptr[d] + pos] = src[e];
    }
}

// ---------- fused gather + MFMA SAGE (+ optional score) ----------
// Block: 256 thr = 4 waves; 16 rows x 128 cols per block. Grid N/16 = 1024.
// Gather: wave wid owns rows wid*4..wid*4+4 via 16-lane subgroups, unroll-4 edge loop,
//         agg row -> 4KB XOR-swizzled LDS tile.
// MFMA:   wave wid owns cols [wid*32, wid*32+32); A from LDS(agg)/global(root).
__global__ __launch_bounds__(256) void sage_fused_kernel(const short* __restrict__ Asrc,
                                                         const short* __restrict__ Bc,
                                                         const float* __restrict__ bias,
                                                         const int* __restrict__ rowptr,
                                                         const int* __restrict__ csr_src,
                                                         const float* __restrict__ invdeg,
                                                         const float* __restrict__ aux,
                                                         short* __restrict__ outb,
                                                         float* __restrict__ outf,
                                                         float* __restrict__ sbuf,
                                                         float* __restrict__ wbuf,
                                                         int relu, int score) {
    __shared__ short aggl[16 * 128];      // 4 KB swizzled
    __shared__ float sdot[16][4];
    __shared__ float snrm[16][4];
    __shared__ float an_s;

    int lane = threadIdx.x & 63;
    int wid = threadIdx.x >> 6;
    int row0 = blockIdx.x * 16;
    int sub = lane >> 4, sl = lane & 15;

    if (score && wid == 0) {
        float2 av = *reinterpret_cast<const float2*>(&aux[lane * 2]);
        float na = av.x * av.x + av.y * av.y;
        for (int m = 1; m < 64; m <<= 1) na += __shfl_xor(na, m);
        if (lane == 0) an_s = fmaxf(sqrtf(na), 1e-8f);
    }

    // ---- gather phase ----
    int r = wid * 4 + sub;
    int node = row0 + r;
    int beg = rowptr[node], end = rowptr[node + 1];
    float acc8[8] = {0.0f, 0.0f, 0.0f, 0.0f, 0.0f, 0.0f, 0.0f, 0.0f};
    int j = beg;
    for (; j + 3 < end; j += 4) {
        int s0 = csr_src[j], s1 = csr_src[j + 1], s2 = csr_src[j + 2], s3 = csr_src[j + 3];
        uint4 v0 = *reinterpret_cast<const uint4*>(&Asrc[(size_t)s0 * D + sl * 8]);
        uint4 v1 = *reinterpret_cast<const uint4*>(&Asrc[(size_t)s1 * D + sl * 8]);
        uint4 v2 = *reinterpret_cast<const uint4*>(&Asrc[(size_t)s2 * D + sl * 8]);
        uint4 v3 = *reinterpret_cast<const uint4*>(&Asrc[(size_t)s3 * D + sl * 8]);
        addv(acc8, v0); addv(acc8, v1); addv(acc8, v2); addv(acc8, v3);
    }
    for (; j < end; j++) {
        int s = csr_src[j];
        uint4 v = *reinterpret_cast<const uint4*>(&Asrc[(size_t)s * D + sl * 8]);
        addv(acc8, v);
    }
    float inv = invdeg[node];
    uint4 o;
    o.x = pk2(acc8[0] * inv, acc8[1] * inv);
    o.y = pk2(acc8[2] * inv, acc8[3] * inv);
    o.z = pk2(acc8[4] * inv, acc8[5] * inv);
    o.w = pk2(acc8[6] * inv, acc8[7] * inv);
    int wbyte = (r * 256 + sl * 16) ^ ((r & 7) << 4);
    *reinterpret_cast<uint4*>(reinterpret_cast<char*>(aggl) + wbyte) = o;
    __syncthreads();

    // ---- MFMA phase ----
    int colbase = wid * 32;
    int rl = lane & 15;
    int kg = lane >> 4;          // 0..3
    int koff = kg * 8;
    int arow_g = row0 + rl;

    f32x4 acc[2];
    acc[0] = (f32x4){0.0f, 0.0f, 0.0f, 0.0f};
    acc[1] = (f32x4){0.0f, 0.0f, 0.0f, 0.0f};

#pragma unroll
    for (int kc = 0; kc < 8; kc++) {
        bf16x8 a;
        if (kc < 4) {
            int rbyte = (rl * 256 + kc * 64 + kg * 16) ^ ((rl & 7) << 4);
            a = *reinterpret_cast<const bf16x8*>(reinterpret_cast<const char*>(aggl) + rbyte);
        } else {
            int k = (kc - 4) * 32 + koff;
            a = *reinterpret_cast<const bf16x8*>(&Asrc[(size_t)arow_g * D + k]);
        }
#pragma unroll
        for (int t = 0; t < 2; t++) {
            int col = colbase + t * 16 + rl;
            bf16x8 b = *reinterpret_cast<const bf16x8*>(&Bc[(size_t)col * 256 + kc * 32 + koff]);
            acc[t] = __builtin_amdgcn_mfma_f32_16x16x32_bf16(a, b, acc[t], 0, 0, 0);
        }
    }

    // ---- epilogue ----
    int rbase = kg * 4;
    float dotp[4] = {0.0f, 0.0f, 0.0f, 0.0f};
    float nrmp[4] = {0.0f, 0.0f, 0.0f, 0.0f};
#pragma unroll
    for (int t = 0; t < 2; t++) {
        int col = colbase + t * 16 + rl;
        float bv = bias[col];
        float av = score ? aux[col] : 0.0f;
#pragma unroll
        for (int rr = 0; rr < 4; rr++) {
            float v = acc[t][rr] + bv;
            if (relu) v = fmaxf(v, 0.0f);
            int grow = row0 + rbase + rr;
            if (outf) outf[(size_t)grow * D + col] = v;
            else outb[(size_t)grow * D + col] = rne_bf16(v);
            dotp[rr] += v * av;
            nrmp[rr] += v * v;
        }
    }

    if (score) {
#pragma unroll
        for (int m = 1; m < 16; m <<= 1) {
#pragma unroll
            for (int rr = 0; rr < 4; rr++) {
                dotp[rr] += __shfl_xor(dotp[rr], m);
                nrmp[rr] += __shfl_xor(nrmp[rr], m);
            }
        }
        if (rl == 0) {
#pragma unroll
            for (int rr = 0; rr < 4; rr++) {
                sdot[rbase + rr][wid] = dotp[rr];
                snrm[rbase + rr][wid] = nrmp[rr];
            }
        }
        __syncthreads();
        int tid = threadIdx.x;
        if (tid < 16) {
            float dot = sdot[tid][0] + sdot[tid][1] + sdot[tid][2] + sdot[tid][3];
            float nh  = snrm[tid][0] + snrm[tid][1] + snrm[tid][2] + snrm[tid][3];
            float hn = fmaxf(sqrtf(nh), 1e-8f);
            float sc = dot / (hn * an_s);
            sbuf[row0 + tid] = sc;
            wbuf[row0 + tid] = expf(-sc * sc);
        }
    }
}

// ---------- moments: 512 threads, 8 waves x 8 rows, LDS cross-wave reduce ----------
__global__ __launch_bounds__(512) void moments_kernel(const float* __restrict__ h,
                                                      const float* __restrict__ sbuf,
                                                      const float* __restrict__ wbuf,
                                                      float* __restrict__ M,
                                                      float* __restrict__ mden, int N) {
    __shared__ float lds[8 * KTERMS * D];     // 64 KB
    __shared__ float ldsm[8 * KTERMS];
    int tid = threadIdx.x;
    int w = tid >> 6, lane = tid & 63;
    int j0 = blockIdx.x * 64 + w * 8;

    float2 acc[KTERMS];
    float macc[KTERMS];
#pragma unroll
    for (int k = 0; k < KTERMS; k++) { acc[k] = make_float2(0.0f, 0.0f); macc[k] = 0.0f; }

    for (int j = j0; j < j0 + 8; j++) {
        float sj = sbuf[j];
        float wj = wbuf[j];
        float2 hv = *reinterpret_cast<const float2*>(&h[(size_t)j * D + lane * 2]);
        float coef = wj;
#pragma unroll
        for (int k = 0; k < KTERMS; k++) {
            acc[k].x += coef * hv.x;
            acc[k].y += coef * hv.y;
            macc[k] += coef;
            coef *= sj;
        }
    }

#pragma unroll
    for (int k = 0; k < KTERMS; k++) {
        lds[(w * KTERMS + k) * D + lane * 2]     = acc[k].x;
        lds[(w * KTERMS + k) * D + lane * 2 + 1] = acc[k].y;
    }
    if (lane == 0) {
#pragma unroll
        for (int k = 0; k < KTERMS; k++) ldsm[w * KTERMS + k] = macc[k];
    }
    __syncthreads();

    for (int e = tid; e < KTERMS * D; e += 512) {
        float s = 0.0f;
#pragma unroll
        for (int ww = 0; ww < 8; ww++) s += lds[ww * KTERMS * D + e];
        atomicAdd(&M[e], s);
    }
    if (tid < KTERMS) {
        float s = 0.0f;
#pragma unroll
        for (int ww = 0; ww < 8; ww++) s += ldsm[ww * KTERMS + tid];
        atomicAdd(&mden[tid], s);
    }
}

// ---------- fused z + classifier: out[n][c] = [h,z]@Wc^T + bc ----------
__global__ __launch_bounds__(128) void zcls_kernel(const float* __restrict__ M,
                                                   const float* __restrict__ mden,
                                                   const float* __restrict__ sbuf,
                                                   const float* __restrict__ h,
                                                   const float* __restrict__ Wc,
                                                   const float* __restrict__ bc,
                                                   float* __restrict__ out, int N) {
    const float A[KTERMS] = {1.0f, 2.0f, 2.0f, 1.3333334f, 0.6666667f, 0.26666668f,
                             0.08888889f, 0.025396826f, 0.0063492064f, 0.0014109347f,
                             2.8218695e-4f, 5.1306718e-5f, 8.5511196e-6f, 1.3155569e-6f,
                             1.8793670e-7f, 2.5058226e-8f};
    __shared__ float Ml[KTERMS * D];
    __shared__ float ml[KTERMS];
    __shared__ float wls[10 * 256];
    __shared__ float red[10][2];
    int tid = threadIdx.x;
    int lane = tid & 63, w = tid >> 6;
#pragma unroll
    for (int k = 0; k < KTERMS; k++) Ml[k * D + tid] = M[k * D + tid];
    if (tid < KTERMS) ml[tid] = mden[tid];
    for (int e = tid; e < 10 * 256; e += 128) wls[e] = Wc[e];
    __syncthreads();

    int n0 = blockIdx.x * 16;
    for (int n = n0; n < n0 + 16; n++) {
        float si = sbuf[n];
        float num = 0.0f, den = 0.0f, p = 1.0f;
#pragma unroll
        for (int k = 0; k < KTERMS; k++) {
            float ck = A[k] * p;
            num += ck * Ml[k * D + tid];
            den += ck * ml[k];
            p *= si;
        }
        float zc = num / den;
        float hc = h[(size_t)n * D + tid];

        float part[10];
#pragma unroll
        for (int c = 0; c < 10; c++)
            part[c] = hc * wls[c * 256 + tid] + zc * wls[c * 256 + 128 + tid];
#pragma unroll
        for (int m = 1; m < 64; m <<= 1) {
#pragma unroll
            for (int c = 0; c < 10; c++) part[c] += __shfl_xor(part[c], m);
        }
        if (lane == 0) {
#pragma unroll
            for (int c = 0; c < 10; c++) red[c][w] = part[c];
        }
        __syncthreads();
        if (tid < 10) out[(size_t)n * 10 + tid] = red[tid][0] + red[tid][1] + bc[tid];
        __syncthreads();
    }
}

extern "C" void kernel_launch(void* const* d_in, const int* in_sizes, int n_in,
                              void* d_out, int out_size, void* d_ws, size_t ws_size,
                              hipStream_t stream) {
    const float* x   = (const float*)d_in[0];
    const int*   ei  = (const int*)d_in[1];
    const float* W1l = (const float*)d_in[2];
    const float* b1l = (const float*)d_in[3];
    const float* W1r = (const float*)d_in[4];
    const float* W2l = (const float*)d_in[5];
    const float* b2l = (const float*)d_in[6];
    const float* W2r = (const float*)d_in[7];
    const float* aux = (const float*)d_in[8];
    const float* Wc  = (const float*)d_in[9];
    const float* bc  = (const float*)d_in[10];
    float* out = (float*)d_out;

    const int N = in_sizes[0] / D;
    const int E = in_sizes[1] / 2;
    const int* srcArr = ei;
    const int* dstArr = ei + E;
    const size_t ND = (size_t)N * D;

    // ---- workspace carve-up ----
    int* ip = (int*)d_ws;
    int* degi    = ip; ip += N;
    int* cursor  = ip; ip += N;
    int* rowptr  = ip; ip += N + 1;
    int* csr_src = ip; ip += E;
    uintptr_t up = ((uintptr_t)ip + 15) & ~(uintptr_t)15;
    short* sp = (short*)up;
    short* xb   = sp; sp += ND;
    short* h1b  = sp; sp += ND;
    short* Bc1  = sp; sp += 128 * 256;
    short* Bc2  = sp; sp += 128 * 256;
    up = ((uintptr_t)sp + 15) & ~(uintptr_t)15;
    float* p = (float*)up;
    float* invdeg = p; p += N;
    float* sbuf   = p; p += N;
    float* wbuf   = p; p += N;
    float* M      = p; p += KTERMS * D;
    float* mden   = p; p += KTERMS;
    float* h2     = p; p += ND;

    // prep: x->bf16, weight concat, zero degi/cursor and M/mden
    prep_kernel<<<1313, 256, 0, stream>>>(x, xb, W1l, W1r, W2l, W2r, Bc1, Bc2, degi, M);

    // build CSR (sorted by dst)
    degi_kernel<<<(E + 255) / 256, 256, 0, stream>>>(dstArr, degi, E);
    scan_kernel<<<1, 1024, 0, stream>>>(degi, rowptr, invdeg, N);
    fill_kernel<<<(E + 255) / 256, 256, 0, stream>>>(srcArr, dstArr, rowptr, cursor, csr_src, E);

    // layer 1: h1b = relu([gather(xb)|xb] @ Bc1^T + b1l)
    sage_fused_kernel<<<N / 16, 256, 0, stream>>>(xb, Bc1, b1l, rowptr, csr_src, invdeg,
                                                  aux, h1b, nullptr, nullptr, nullptr, 1, 0);
    // layer 2: h2 = [gather(h1b)|h1b] @ Bc2^T + b2l, + score epilogue
    sage_fused_kernel<<<N / 16, 256, 0, stream>>>(h1b, Bc2, b2l, rowptr, csr_src, invdeg,
                                                  aux, nullptr, h2, sbuf, wbuf, 0, 1);

    // Taylor moments
    moments_kernel<<<N / 64, 512, 0, stream>>>(h2, sbuf, wbuf, M, mden, N);

    // fused z + classifier
    zcls_kernel<<<N / 16, 128, 0, stream>>>(M, mden, sbuf, h2, Wc, bc, out, N);
}